// Round 2
// baseline (320.630 us; speedup 1.0000x reference)
//
#include <hip/hip_runtime.h>
#include <hip/hip_bf16.h>

typedef __attribute__((ext_vector_type(8))) short bf16x8;
typedef __attribute__((ext_vector_type(4))) short bf16x4;
typedef __attribute__((ext_vector_type(4))) float f32x4;

#define DEVI static __device__ __forceinline__

constexpr int NAG = 32, DIN = 256, HDIM = 128, ADIM = 32;
constexpr int G = 2;          // batch elems per block

// ws layout (bf16 element offsets)
constexpr int WS_ENC = 0;                  // 256x128 -> 32768
constexpr int WS_H   = 32768;              // 8 mats x 16384
constexpr int WS_QW  = 32768 + 8 * 16384;  // 163840, 4096 elems
constexpr int WS_TOT = WS_QW + 4096;       // 167936

// LDS byte offsets (total 54272 -> 3 blocks/CU)
constexpr int L_R0 = 0;          // 64x136 bf16 = 17408
constexpr int L_R1 = 17408;      // 64x136 bf16 = 17408
constexpr int L_R2 = 34816;      // k 64x136 / vT 128x72 bf16 = 18432
constexpr int L_ST = 53248;      // 64 rows x 4 floats = 1024
constexpr int L_TOT = 54272;

DEVI short f2bf(float f) {
  union { float f; unsigned u; } a; a.f = f;
  unsigned r = (a.u + 0x7fffu + ((a.u >> 16) & 1u)) >> 16;
  return (short)r;
}

// ---------------- weight prep: fp32 row-major -> bf16 MFMA B-fragment order ----
// frag element e = ((ks*NT + nt)*64 + lane)*8 + j  maps to  W[ks*32+(lane>>4)*8+j][nt*16+(lane&15)]
__global__ void prep_weights(const float* __restrict__ enc_w,
                             const float* __restrict__ m0, const float* __restrict__ m1,
                             const float* __restrict__ m2, const float* __restrict__ m3,
                             const float* __restrict__ m4, const float* __restrict__ m5,
                             const float* __restrict__ m6, const float* __restrict__ m7,
                             const float* __restrict__ qw,
                             short* __restrict__ ws)
{
  const int i = blockIdx.x * 256 + threadIdx.x;
  if (i >= WS_TOT) return;
  const float* src; int Nout, e, base, sh, ntm;
  if (i < 32768) { src = enc_w; Nout = 128; e = i; base = 0; sh = 3; ntm = 7; }
  else if (i < WS_QW) {
    const int m = (i - 32768) >> 14;
    e = (i - 32768) & 16383; base = 32768 + (m << 14);
    const float* tab[8] = {m0, m1, m2, m3, m4, m5, m6, m7};
    src = tab[m]; Nout = 128; sh = 3; ntm = 7;
  } else { src = qw; Nout = 32; e = i - WS_QW; base = WS_QW; sh = 1; ntm = 1; }
  const int j = e & 7, lane = (e >> 3) & 63, tile = e >> 9;
  const int nt = tile & ntm, ks = tile >> sh;
  const int row = ks * 32 + (lane >> 4) * 8 + j;
  const int col = nt * 16 + (lane & 15);
  ws[base + e] = f2bf(src[row * Nout + col]);
}

// ---------------- per-wave linear: dst = act(src[64xK] @ W[Kx128] + b) ---------
// wave w (of 8) computes output cols [16w, 16w+16)
template<int KSTEPS, bool RELU, bool TRANS>
DEVI void linearW(const short* __restrict__ src, int sstride,
                  const short* __restrict__ wfrag, const float* __restrict__ bias,
                  short* __restrict__ dst, int dstride,
                  int wave, int lr, int lq, int lane)
{
  f32x4 acc[4];
#pragma unroll
  for (int mt = 0; mt < 4; ++mt) acc[mt] = (f32x4){0.f, 0.f, 0.f, 0.f};

  const bf16x8* wp = (const bf16x8*)wfrag;
  bf16x8 bcur = wp[(0 * 8 + wave) * 64 + lane];
#pragma unroll
  for (int ks = 0; ks < KSTEPS; ++ks) {
    bf16x8 bnxt = bcur;
    if (ks + 1 < KSTEPS) bnxt = wp[((ks + 1) * 8 + wave) * 64 + lane];
    bf16x8 af[4];
#pragma unroll
    for (int mt = 0; mt < 4; ++mt)
      af[mt] = *(const bf16x8*)(src + (mt * 16 + lr) * sstride + ks * 32 + lq * 8);
#pragma unroll
    for (int mt = 0; mt < 4; ++mt)
      acc[mt] = __builtin_amdgcn_mfma_f32_16x16x32_bf16(af[mt], bcur, acc[mt], 0, 0, 0);
    bcur = bnxt;
  }

  const int col = wave * 16 + lr;
  const float bv = bias[col];
#pragma unroll
  for (int mt = 0; mt < 4; ++mt) {
    if (!TRANS) {
#pragma unroll
      for (int r = 0; r < 4; ++r) {
        float v = acc[mt][r] + bv;
        if (RELU) v = fmaxf(v, 0.f);
        dst[(mt * 16 + lq * 4 + r) * dstride + col] = f2bf(v);
      }
    } else {           // transposed store (for v): dst[col][row], 4 consecutive rows
      bf16x4 s;
#pragma unroll
      for (int r = 0; r < 4; ++r) {
        float v = acc[mt][r] + bv;
        if (RELU) v = fmaxf(v, 0.f);
        s[r] = f2bf(v);
      }
      *(bf16x4*)(dst + col * dstride + mt * 16 + lq * 4) = s;
    }
  }
}

// ---------------- one attention block, fully in LDS ----------------------------
// h lives in Rh; produces h' in Rq (caller swaps roles next block)
DEVI void att_block(short* Rh, short* Rq, short* R2, float* ST,
                    const short* wv, const short* wk, const short* wq, const short* wo,
                    const float* bv, const float* bk, const float* bq, const float* bo,
                    const float* __restrict__ mask, int b0,
                    int wave, int lr, int lq, int lane)
{
  linearW<4, true, false>(Rh, 136, wq, bq, Rq, 136, wave, lr, lq, lane);  // q -> Rq
  linearW<4, true, false>(Rh, 136, wk, bk, R2, 136, wave, lr, lq, lane);  // k -> R2
  __syncthreads();

  // scores: wave = (g, mt, nt); tile rows [g*32+mt*16, +16), cols [nt*16, +16)
  const int g = wave >> 2, smt = (wave >> 1) & 1, snt = wave & 1;
  float lg[4];
  {
    f32x4 sacc = (f32x4){0, 0, 0, 0};
#pragma unroll
    for (int ks = 0; ks < 4; ++ks) {
      const bf16x8 qf = *(const bf16x8*)(Rq + (g * 32 + smt * 16 + lr) * 136 + ks * 32 + lq * 8);
      const bf16x8 kf = *(const bf16x8*)(R2 + (g * 32 + snt * 16 + lr) * 136 + ks * 32 + lq * 8);
      sacc = __builtin_amdgcn_mfma_f32_16x16x32_bf16(qf, kf, sacc, 0, 0, 0);
    }
    const float* mp = mask + (size_t)(b0 + g) * (NAG * NAG);
#pragma unroll
    for (int r = 0; r < 4; ++r) {
      const int row = smt * 16 + lq * 4 + r, col = snt * 16 + lr;
      const float m = mp[row * 32 + col];
      const float l = sacc[r] * m - 9e15f * (1.f - m);
      lg[r] = l;
      float v = l;
      v = fmaxf(v, __shfl_xor(v, 1)); v = fmaxf(v, __shfl_xor(v, 2));
      v = fmaxf(v, __shfl_xor(v, 4)); v = fmaxf(v, __shfl_xor(v, 8));
      float e = __expf(l - v);
      e += __shfl_xor(e, 1); e += __shfl_xor(e, 2);
      e += __shfl_xor(e, 4); e += __shfl_xor(e, 8);
      if (lr == 0) {
        float2 p; p.x = v; p.y = e;
        *(float2*)(ST + (g * 32 + row) * 4 + snt * 2) = p;  // ST[row] = {m0,s0,m1,s1}
      }
    }
  }
  __syncthreads();

  // combine halves -> normalized att (bf16) into AT (= Rq region, q is dead)
  short* AT = Rq;
#pragma unroll
  for (int r = 0; r < 4; ++r) {
    const int row = g * 32 + smt * 16 + lq * 4 + r, col = snt * 16 + lr;
    const float4 s4 = *(const float4*)(ST + row * 4);
    const float M = fmaxf(s4.x, s4.z);
    const float T = s4.y * __expf(s4.x - M) + s4.w * __expf(s4.z - M);
    const float a = __expf(lg[r] - M) / T;
    AT[row * 40 + col] = f2bf(a);
  }

  // v -> R2 stored TRANSPOSED as vT[128][72] (k is dead)
  linearW<4, true, true>(Rh, 136, wv, bv, R2, 72, wave, lr, lq, lane);
  __syncthreads();

  // out = att @ v; wave = (g, cq): rows of group g, cols [cq*32, +32). h is dead -> Rh
  {
    const int cq = wave & 3, pg = wave >> 2;
    f32x4 acc[2][2];
#pragma unroll
    for (int mt = 0; mt < 2; ++mt)
#pragma unroll
      for (int nt = 0; nt < 2; ++nt) acc[mt][nt] = (f32x4){0, 0, 0, 0};
    bf16x8 pa[2];
#pragma unroll
    for (int mt = 0; mt < 2; ++mt)
      pa[mt] = *(const bf16x8*)(AT + (pg * 32 + mt * 16 + lr) * 40 + lq * 8);
#pragma unroll
    for (int nt = 0; nt < 2; ++nt) {
      const bf16x8 vf = *(const bf16x8*)(R2 + (cq * 32 + nt * 16 + lr) * 72 + pg * 32 + lq * 8);
#pragma unroll
      for (int mt = 0; mt < 2; ++mt)
        acc[mt][nt] = __builtin_amdgcn_mfma_f32_16x16x32_bf16(pa[mt], vf, acc[mt][nt], 0, 0, 0);
    }
#pragma unroll
    for (int nt = 0; nt < 2; ++nt)
#pragma unroll
      for (int mt = 0; mt < 2; ++mt)
#pragma unroll
        for (int r = 0; r < 4; ++r) {
          const int row = pg * 32 + mt * 16 + lq * 4 + r;
          const int col = cq * 32 + nt * 16 + lr;
          Rh[row * 136 + col] = f2bf(acc[mt][nt][r]);
        }
  }
  __syncthreads();

  linearW<4, true, false>(Rh, 136, wo, bo, Rq, 136, wave, lr, lq, lane);  // h' -> Rq
  __syncthreads();
}

// ---------------- fused forward: one block (512 thr) = 2 batch elements --------
__global__ __launch_bounds__(512, 6)
void dgn_main(const float* __restrict__ x, const float* __restrict__ mask,
              const float* __restrict__ enc_b,
              const float* __restrict__ b1v, const float* __restrict__ b1k,
              const float* __restrict__ b1q, const float* __restrict__ b1o,
              const float* __restrict__ b2v, const float* __restrict__ b2k,
              const float* __restrict__ b2q, const float* __restrict__ b2o,
              const float* __restrict__ qb,
              const short* __restrict__ wf,
              float* __restrict__ out)
{
  __shared__ __align__(16) char smem[L_TOT];
  short* R0 = (short*)(smem + L_R0);
  short* R1 = (short*)(smem + L_R1);
  short* R2 = (short*)(smem + L_R2);
  float* ST = (float*)(smem + L_ST);
  short* XB = (short*)(smem + L_R1);   // x staging [64][264] spans R1+R2 (33792 B)

  const int tid = threadIdx.x;
  const int wave = tid >> 6, lane = tid & 63;
  const int lr = lane & 15, lq = lane >> 4;
  const int b0 = blockIdx.x * G;

  // stage x (fp32 -> bf16) into XB
  {
    const float4* xsrc = (const float4*)(x + (size_t)b0 * NAG * DIN);
#pragma unroll
    for (int it = 0; it < 8; ++it) {
      const int q4 = tid + it * 512;
      const float4 v = xsrc[q4];
      const int row = q4 >> 6;
      const int col = (q4 & 63) * 4;
      bf16x4 s;
      s[0] = f2bf(v.x); s[1] = f2bf(v.y); s[2] = f2bf(v.z); s[3] = f2bf(v.w);
      *(bf16x4*)(XB + row * 264 + col) = s;
    }
  }
  __syncthreads();

  // encoder: h1 = relu(x @ enc_w + enc_b) -> R0
  linearW<8, true, false>(XB, 264, wf + WS_ENC, enc_b, R0, 136, wave, lr, lq, lane);
  __syncthreads();

  att_block(R0, R1, R2, ST,
            wf + WS_H + 0 * 16384, wf + WS_H + 1 * 16384,
            wf + WS_H + 2 * 16384, wf + WS_H + 3 * 16384,
            b1v, b1k, b1q, b1o, mask, b0, wave, lr, lq, lane);   // h' -> R1

  att_block(R1, R0, R2, ST,
            wf + WS_H + 4 * 16384, wf + WS_H + 5 * 16384,
            wf + WS_H + 6 * 16384, wf + WS_H + 7 * 16384,
            b2v, b2k, b2q, b2o, mask, b0, wave, lr, lq, lane);   // h'' -> R0

  // head: out = h'' @ q_w + q_b; wave = (mt, t): rows [16mt,+16), cols [16t,+16)
  {
    const int hmt = wave >> 1, ht = wave & 1;
    f32x4 facc = (f32x4){0, 0, 0, 0};
    const bf16x8* wp = (const bf16x8*)(wf + WS_QW);
    bf16x8 bq[4];
#pragma unroll
    for (int ks = 0; ks < 4; ++ks)
      bq[ks] = wp[(ks * 2 + ht) * 64 + lane];
#pragma unroll
    for (int ks = 0; ks < 4; ++ks) {
      const bf16x8 af = *(const bf16x8*)(R0 + (hmt * 16 + lr) * 136 + ks * 32 + lq * 8);
      facc = __builtin_amdgcn_mfma_f32_16x16x32_bf16(af, bq[ks], facc, 0, 0, 0);
    }
    const int col = ht * 16 + lr;
    const float bvv = qb[col];
#pragma unroll
    for (int r = 0; r < 4; ++r) {
      const int row = hmt * 16 + lq * 4 + r;           // 0..63
      const int gg = row >> 5, ag = row & 31;
      out[(((size_t)(b0 + gg) * NAG) + ag) * ADIM + col] = facc[r] + bvv;
    }
  }
}

extern "C" void kernel_launch(void* const* d_in, const int* in_sizes, int n_in,
                              void* d_out, int out_size, void* d_ws, size_t ws_size,
                              hipStream_t stream)
{
  const float* x     = (const float*)d_in[0];
  const float* mask  = (const float*)d_in[1];
  const float* enc_w = (const float*)d_in[2];
  const float* enc_b = (const float*)d_in[3];
  const float* a1_vw = (const float*)d_in[4];
  const float* a1_vb = (const float*)d_in[5];
  const float* a1_kw = (const float*)d_in[6];
  const float* a1_kb = (const float*)d_in[7];
  const float* a1_qw = (const float*)d_in[8];
  const float* a1_qb = (const float*)d_in[9];
  const float* a1_ow = (const float*)d_in[10];
  const float* a1_ob = (const float*)d_in[11];
  const float* a2_vw = (const float*)d_in[12];
  const float* a2_vb = (const float*)d_in[13];
  const float* a2_kw = (const float*)d_in[14];
  const float* a2_kb = (const float*)d_in[15];
  const float* a2_qw = (const float*)d_in[16];
  const float* a2_qb = (const float*)d_in[17];
  const float* a2_ow = (const float*)d_in[18];
  const float* a2_ob = (const float*)d_in[19];
  const float* q_w   = (const float*)d_in[20];
  const float* q_b   = (const float*)d_in[21];
  short* ws = (short*)d_ws;

  prep_weights<<<(WS_TOT + 255) / 256, 256, 0, stream>>>(
      enc_w, a1_vw, a1_kw, a1_qw, a1_ow, a2_vw, a2_kw, a2_qw, a2_ow, q_w, ws);

  dgn_main<<<4096 / G, 512, 0, stream>>>(
      x, mask, enc_b,
      a1_vb, a1_kb, a1_qb, a1_ob,
      a2_vb, a2_kb, a2_qb, a2_ob,
      q_b, ws, (float*)d_out);
}

// Round 3
// 313.221 us; speedup vs baseline: 1.0237x; 1.0237x over previous
//
#include <hip/hip_runtime.h>
#include <hip/hip_bf16.h>

typedef __attribute__((ext_vector_type(8))) short bf16x8;
typedef __attribute__((ext_vector_type(4))) short bf16x4;
typedef __attribute__((ext_vector_type(4))) float f32x4;

#define DEVI static __device__ __forceinline__

constexpr int NAG = 32, DIN = 256, HDIM = 128, ADIM = 32;
constexpr int G = 2;

// ws layout (bf16 element offsets). Frag order (same formula serves A- and
// B-orientation since lane->(idx&15,kchunk) maps coincide):
//   elem ((ks*NM + mt)*64 + lane)*8 + j  <->  W[ks*32 + (lane>>4)*8 + j][mt*16 + (lane&15)]
constexpr int WS_ENC = 0;                  // 256x128
constexpr int WS_H   = 32768;              // 8 mats x 16384
constexpr int WS_QW  = 32768 + 8 * 16384;  // 128x32
constexpr int WS_TOT = WS_QW + 4096;

// strides (shorts)
constexpr int SH = 136;   // h/Q/K/attout rows [64][136]
constexpr int SV = 72;    // vT rows [128][72]
constexpr int SA = 40;    // AT rows [64][40]
constexpr int SX = 264;   // x staging [64][264]

// LDS byte offsets (total 75776 -> 2 blocks/CU)
constexpr int L_R0 = 0;
constexpr int L_R1 = 17408;
constexpr int L_R2 = 34816;
constexpr int L_RV = 52224;   // 128*72*2 = 18432
constexpr int L_AT = 70656;   // 64*40*2  = 5120
constexpr int L_TOT = 75776;

DEVI short f2bf(float f) {
  union { float f; unsigned u; } a; a.f = f;
  return (short)((a.u + 0x7fffu + ((a.u >> 16) & 1u)) >> 16);
}

// ---------------- weight prep: coalesced float4 reads, scattered 2B writes ----
__global__ void prep_weights(const float* __restrict__ enc_w,
                             const float* __restrict__ m0, const float* __restrict__ m1,
                             const float* __restrict__ m2, const float* __restrict__ m3,
                             const float* __restrict__ m4, const float* __restrict__ m5,
                             const float* __restrict__ m6, const float* __restrict__ m7,
                             const float* __restrict__ qw,
                             short* __restrict__ ws)
{
  const int blk = blockIdx.x, tid = threadIdx.x;
  const float* src; int base, NM, nsh, f4;
  if (blk < 32) { src = enc_w; base = WS_ENC; NM = 8; nsh = 7; f4 = blk * 256 + tid; }
  else if (blk < 160) {
    const int m = (blk - 32) >> 4;
    if      (m == 0) src = m0; else if (m == 1) src = m1;
    else if (m == 2) src = m2; else if (m == 3) src = m3;
    else if (m == 4) src = m4; else if (m == 5) src = m5;
    else if (m == 6) src = m6; else             src = m7;
    base = WS_H + (m << 14); NM = 8; nsh = 7; f4 = ((blk - 32) & 15) * 256 + tid;
  } else { src = qw; base = WS_QW; NM = 2; nsh = 5; f4 = (blk - 160) * 256 + tid; }
  const int s = f4 * 4;
  const int row = s >> nsh, col0 = s & ((1 << nsh) - 1);
  const float4 v = *(const float4*)(src + s);
  const int j = row & 7, ks = row >> 5, lhi = ((row >> 3) & 3) * 16;
  const float vv[4] = {v.x, v.y, v.z, v.w};
#pragma unroll
  for (int c = 0; c < 4; ++c) {
    const int col = col0 + c;
    const int mt = col >> 4, lane = lhi + (col & 15);
    ws[base + (((ks * NM + mt) * 64 + lane) << 3) + j] = f2bf(vv[c]);
  }
}

// ---------------- swapped linear: dst[agent][feat] = act(W^T-as-A, src-as-B) ---
// wave w: m-tiles (features) mg*2+{0,1}, n-tiles (agents) ng*2+{0,1}
template<int KSTEPS, bool RELU>
DEVI void linearSw(const short* __restrict__ src, int sstride,
                   const short* __restrict__ wfrag, const float* __restrict__ bias,
                   short* __restrict__ dst,
                   int wave, int lr, int lq, int lane)
{
  const int mg = wave >> 1, ng = wave & 1;
  f32x4 acc[2][2];
#pragma unroll
  for (int a = 0; a < 2; ++a)
#pragma unroll
    for (int b = 0; b < 2; ++b) acc[a][b] = (f32x4){0.f, 0.f, 0.f, 0.f};

  const bf16x8* wp = (const bf16x8*)wfrag;
#pragma unroll
  for (int ks = 0; ks < KSTEPS; ++ks) {
    bf16x8 hb[2];
#pragma unroll
    for (int b = 0; b < 2; ++b)
      hb[b] = *(const bf16x8*)(src + ((ng * 2 + b) * 16 + lr) * sstride + ks * 32 + lq * 8);
    bf16x8 wa[2];
#pragma unroll
    for (int a = 0; a < 2; ++a)
      wa[a] = wp[(ks * 8 + mg * 2 + a) * 64 + lane];
#pragma unroll
    for (int a = 0; a < 2; ++a)
#pragma unroll
      for (int b = 0; b < 2; ++b)
        acc[a][b] = __builtin_amdgcn_mfma_f32_16x16x32_bf16(wa[a], hb[b], acc[a][b], 0, 0, 0);
  }
#pragma unroll
  for (int a = 0; a < 2; ++a) {
    const float4 bv = *(const float4*)(bias + (mg * 2 + a) * 16 + lq * 4);
    const float bb[4] = {bv.x, bv.y, bv.z, bv.w};
#pragma unroll
    for (int b = 0; b < 2; ++b) {
      bf16x4 s;
#pragma unroll
      for (int r = 0; r < 4; ++r) {
        float v = acc[a][b][r] + bb[r];
        if (RELU) v = fmaxf(v, 0.f);
        s[r] = f2bf(v);
      }
      *(bf16x4*)(dst + ((ng * 2 + b) * 16 + lr) * SH + (mg * 2 + a) * 16 + lq * 4) = s;
    }
  }
}

// ---------------- fused QKV: one h-read pass feeds q,k (swapped) and v (normal) -
DEVI void qkv_pass(const short* __restrict__ h,
                   const short* __restrict__ wq, const short* __restrict__ wk,
                   const short* __restrict__ wv,
                   const float* __restrict__ bq, const float* __restrict__ bk,
                   const float* __restrict__ bv,
                   short* __restrict__ Q, short* __restrict__ K, short* __restrict__ V,
                   int wave, int lr, int lq, int lane)
{
  const int mg = wave >> 1, ng = wave & 1;
  f32x4 qa[2][2], ka[2][2], va[2][2];
#pragma unroll
  for (int a = 0; a < 2; ++a)
#pragma unroll
    for (int b = 0; b < 2; ++b) {
      qa[a][b] = (f32x4){0.f, 0.f, 0.f, 0.f};
      ka[a][b] = (f32x4){0.f, 0.f, 0.f, 0.f};
      va[a][b] = (f32x4){0.f, 0.f, 0.f, 0.f};
    }
  const bf16x8* wpq = (const bf16x8*)wq;
  const bf16x8* wpk = (const bf16x8*)wk;
  const bf16x8* wpv = (const bf16x8*)wv;
#pragma unroll
  for (int ks = 0; ks < 4; ++ks) {
    bf16x8 hf[2];
#pragma unroll
    for (int b = 0; b < 2; ++b)
      hf[b] = *(const bf16x8*)(h + ((ng * 2 + b) * 16 + lr) * SH + ks * 32 + lq * 8);
#pragma unroll
    for (int a = 0; a < 2; ++a) {
      const bf16x8 wqf = wpq[(ks * 8 + mg * 2 + a) * 64 + lane];
      const bf16x8 wkf = wpk[(ks * 8 + mg * 2 + a) * 64 + lane];
      const bf16x8 wvf = wpv[(ks * 8 + mg * 2 + a) * 64 + lane];
#pragma unroll
      for (int b = 0; b < 2; ++b) {
        qa[a][b] = __builtin_amdgcn_mfma_f32_16x16x32_bf16(wqf, hf[b], qa[a][b], 0, 0, 0);
        ka[a][b] = __builtin_amdgcn_mfma_f32_16x16x32_bf16(wkf, hf[b], ka[a][b], 0, 0, 0);
        va[b][a] = __builtin_amdgcn_mfma_f32_16x16x32_bf16(hf[b], wvf, va[b][a], 0, 0, 0);
      }
    }
  }
  // q, k epilogues: lane holds 4 consecutive features for fixed agent
#pragma unroll
  for (int a = 0; a < 2; ++a) {
    const float4 bq4 = *(const float4*)(bq + (mg * 2 + a) * 16 + lq * 4);
    const float4 bk4 = *(const float4*)(bk + (mg * 2 + a) * 16 + lq * 4);
    const float qb4[4] = {bq4.x, bq4.y, bq4.z, bq4.w};
    const float kb4[4] = {bk4.x, bk4.y, bk4.z, bk4.w};
#pragma unroll
    for (int b = 0; b < 2; ++b) {
      bf16x4 sq, sk;
#pragma unroll
      for (int r = 0; r < 4; ++r) {
        sq[r] = f2bf(fmaxf(qa[a][b][r] + qb4[r], 0.f));
        sk[r] = f2bf(fmaxf(ka[a][b][r] + kb4[r], 0.f));
      }
      const int off = ((ng * 2 + b) * 16 + lr) * SH + (mg * 2 + a) * 16 + lq * 4;
      *(bf16x4*)(Q + off) = sq;
      *(bf16x4*)(K + off) = sk;
    }
  }
  // v epilogue: normal orientation -> lane holds 4 consecutive agents for fixed feature
#pragma unroll
  for (int a = 0; a < 2; ++a) {
    const float bvv = bv[(mg * 2 + a) * 16 + lr];
#pragma unroll
    for (int b = 0; b < 2; ++b) {
      bf16x4 sv;
#pragma unroll
      for (int r = 0; r < 4; ++r)
        sv[r] = f2bf(fmaxf(va[b][a][r] + bvv, 0.f));
      *(bf16x4*)(V + ((mg * 2 + a) * 16 + lr) * SV + (ng * 2 + b) * 16 + lq * 4) = sv;
    }
  }
}

// ---------------- scores + softmax on 4 waves, fully in-register ----------------
DEVI void scores_pass(const short* __restrict__ Q, const short* __restrict__ K,
                      short* __restrict__ AT, const float* __restrict__ mask, int b0,
                      int wave, int lr, int lq, int lane)
{
  const int g = wave >> 1, qt = wave & 1;
  f32x4 sc[2];
  sc[0] = (f32x4){0.f, 0.f, 0.f, 0.f};
  sc[1] = (f32x4){0.f, 0.f, 0.f, 0.f};
#pragma unroll
  for (int ks = 0; ks < 4; ++ks) {
    const bf16x8 qf = *(const bf16x8*)(Q + (g * 32 + qt * 16 + lr) * SH + ks * 32 + lq * 8);
#pragma unroll
    for (int kt = 0; kt < 2; ++kt) {
      const bf16x8 kf = *(const bf16x8*)(K + (g * 32 + kt * 16 + lr) * SH + ks * 32 + lq * 8);
      sc[kt] = __builtin_amdgcn_mfma_f32_16x16x32_bf16(kf, qf, sc[kt], 0, 0, 0);
    }
  }
  // lane holds q = qt*16+lr (fixed), k = kt*16 + lq*4 + r  (8 logits)
  const float* mp = mask + (size_t)(b0 + g) * (NAG * NAG) + (qt * 16 + lr) * 32;
  float l[2][4];
  float M = -3.0e38f;
#pragma unroll
  for (int kt = 0; kt < 2; ++kt) {
    const float4 m4 = *(const float4*)(mp + kt * 16 + lq * 4);
    const float mm[4] = {m4.x, m4.y, m4.z, m4.w};
#pragma unroll
    for (int r = 0; r < 4; ++r) {
      const float v = sc[kt][r] * mm[r] - 9e15f * (1.f - mm[r]);
      l[kt][r] = v;
      M = fmaxf(M, v);
    }
  }
  M = fmaxf(M, __shfl_xor(M, 16));
  M = fmaxf(M, __shfl_xor(M, 32));
  float e[2][4], T = 0.f;
#pragma unroll
  for (int kt = 0; kt < 2; ++kt)
#pragma unroll
    for (int r = 0; r < 4; ++r) { e[kt][r] = __expf(l[kt][r] - M); T += e[kt][r]; }
  T += __shfl_xor(T, 16);
  T += __shfl_xor(T, 32);
  const float rT = __frcp_rn(T);
#pragma unroll
  for (int kt = 0; kt < 2; ++kt) {
    bf16x4 s;
#pragma unroll
    for (int r = 0; r < 4; ++r) s[r] = f2bf(e[kt][r] * rT);
    *(bf16x4*)(AT + (g * 32 + qt * 16 + lr) * SA + kt * 16 + lq * 4) = s;
  }
}

// ---------------- PV: attout[q][feat] = att @ v  (A=vT, B=AT) -------------------
DEVI void pv_pass(const short* __restrict__ V, const short* __restrict__ AT,
                  short* __restrict__ AO, int wave, int lr, int lq, int lane)
{
  const int g = wave >> 2, qt = (wave >> 1) & 1, fh = wave & 1;
  const bf16x8 atf = *(const bf16x8*)(AT + (g * 32 + qt * 16 + lr) * SA + lq * 8);
  f32x4 pacc[4];
#pragma unroll
  for (int f = 0; f < 4; ++f) {
    const int ft = fh * 4 + f;
    const bf16x8 vf = *(const bf16x8*)(V + (ft * 16 + lr) * SV + g * 32 + lq * 8);
    pacc[f] = __builtin_amdgcn_mfma_f32_16x16x32_bf16(
        vf, atf, (f32x4){0.f, 0.f, 0.f, 0.f}, 0, 0, 0);
  }
#pragma unroll
  for (int f = 0; f < 4; ++f) {
    const int ft = fh * 4 + f;
    bf16x4 s;
#pragma unroll
    for (int r = 0; r < 4; ++r) s[r] = f2bf(pacc[f][r]);
    *(bf16x4*)(AO + (g * 32 + qt * 16 + lr) * SH + ft * 16 + lq * 4) = s;
  }
}

DEVI void att_block(short* Rh, short* Rq, short* RK, short* RV_, short* ATb,
                    const short* wv, const short* wk, const short* wq, const short* wo,
                    const float* bv, const float* bk, const float* bq, const float* bo,
                    const float* __restrict__ mask, int b0,
                    int wave, int lr, int lq, int lane)
{
  qkv_pass(Rh, wq, wk, wv, bq, bk, bv, Rq, RK, RV_, wave, lr, lq, lane);
  __syncthreads();
  if (wave < 4) scores_pass(Rq, RK, ATb, mask, b0, wave, lr, lq, lane);
  __syncthreads();
  pv_pass(RV_, ATb, Rh, wave, lr, lq, lane);   // attout -> Rh (h dead)
  __syncthreads();
  linearSw<4, true>(Rh, SH, wo, bo, Rq, wave, lr, lq, lane);  // h' -> Rq
  __syncthreads();
}

// ---------------- fused forward: one block (512 thr) = 2 batch elements --------
__global__ __launch_bounds__(512, 4)
void dgn_main(const float* __restrict__ x, const float* __restrict__ mask,
              const float* __restrict__ enc_b,
              const float* __restrict__ b1v, const float* __restrict__ b1k,
              const float* __restrict__ b1q, const float* __restrict__ b1o,
              const float* __restrict__ b2v, const float* __restrict__ b2k,
              const float* __restrict__ b2q, const float* __restrict__ b2o,
              const float* __restrict__ qb,
              const short* __restrict__ wf,
              float* __restrict__ out)
{
  __shared__ __align__(16) char smem[L_TOT];
  short* R0 = (short*)(smem + L_R0);
  short* R1 = (short*)(smem + L_R1);
  short* R2 = (short*)(smem + L_R2);
  short* RV_ = (short*)(smem + L_RV);
  short* ATb = (short*)(smem + L_AT);
  short* XB = (short*)(smem + L_R1);   // x staging [64][264] = 33792 B over R1+R2

  const int tid = threadIdx.x;
  const int wave = tid >> 6, lane = tid & 63;
  const int lr = lane & 15, lq = lane >> 4;
  const int b0 = blockIdx.x * G;

  // stage x (fp32 -> bf16)
  {
    const float4* xsrc = (const float4*)(x + (size_t)b0 * NAG * DIN);
#pragma unroll
    for (int it = 0; it < 8; ++it) {
      const int q4 = tid + it * 512;
      const float4 v = xsrc[q4];
      bf16x4 s;
      s[0] = f2bf(v.x); s[1] = f2bf(v.y); s[2] = f2bf(v.z); s[3] = f2bf(v.w);
      *(bf16x4*)(XB + (q4 >> 6) * SX + (q4 & 63) * 4) = s;
    }
  }
  __syncthreads();

  // encoder (swapped): h1[agent][feat] -> R0
  linearSw<8, true>(XB, SX, wf + WS_ENC, enc_b, R0, wave, lr, lq, lane);
  __syncthreads();

  att_block(R0, R1, R2, RV_, ATb,
            wf + WS_H + 0 * 16384, wf + WS_H + 1 * 16384,
            wf + WS_H + 2 * 16384, wf + WS_H + 3 * 16384,
            b1v, b1k, b1q, b1o, mask, b0, wave, lr, lq, lane);   // h' -> R1

  att_block(R1, R0, R2, RV_, ATb,
            wf + WS_H + 4 * 16384, wf + WS_H + 5 * 16384,
            wf + WS_H + 6 * 16384, wf + WS_H + 7 * 16384,
            b2v, b2k, b2q, b2o, mask, b0, wave, lr, lq, lane);   // h'' -> R0

  // head on 4 waves: full 128-B output lines per wave
  if (wave < 4) {
    f32x4 ha[2];
    ha[0] = (f32x4){0.f, 0.f, 0.f, 0.f};
    ha[1] = (f32x4){0.f, 0.f, 0.f, 0.f};
    const bf16x8* wp = (const bf16x8*)(wf + WS_QW);
#pragma unroll
    for (int ks = 0; ks < 4; ++ks) {
      const bf16x8 hf = *(const bf16x8*)(R0 + (wave * 16 + lr) * SH + ks * 32 + lq * 8);
#pragma unroll
      for (int a = 0; a < 2; ++a)
        ha[a] = __builtin_amdgcn_mfma_f32_16x16x32_bf16(wp[(ks * 2 + a) * 64 + lane], hf, ha[a], 0, 0, 0);
    }
    const int row = wave * 16 + lr;                 // 0..63
    float* op = out + (((size_t)(b0 + (row >> 5)) * NAG) + (row & 31)) * ADIM;
#pragma unroll
    for (int a = 0; a < 2; ++a) {
      const float4 bv4 = *(const float4*)(qb + a * 16 + lq * 4);
      float4 o;
      o.x = ha[a][0] + bv4.x; o.y = ha[a][1] + bv4.y;
      o.z = ha[a][2] + bv4.z; o.w = ha[a][3] + bv4.w;
      *(float4*)(op + a * 16 + lq * 4) = o;
    }
  }
}

extern "C" void kernel_launch(void* const* d_in, const int* in_sizes, int n_in,
                              void* d_out, int out_size, void* d_ws, size_t ws_size,
                              hipStream_t stream)
{
  const float* x     = (const float*)d_in[0];
  const float* mask  = (const float*)d_in[1];
  const float* enc_w = (const float*)d_in[2];
  const float* enc_b = (const float*)d_in[3];
  const float* a1_vw = (const float*)d_in[4];
  const float* a1_vb = (const float*)d_in[5];
  const float* a1_kw = (const float*)d_in[6];
  const float* a1_kb = (const float*)d_in[7];
  const float* a1_qw = (const float*)d_in[8];
  const float* a1_qb = (const float*)d_in[9];
  const float* a1_ow = (const float*)d_in[10];
  const float* a1_ob = (const float*)d_in[11];
  const float* a2_vw = (const float*)d_in[12];
  const float* a2_vb = (const float*)d_in[13];
  const float* a2_kw = (const float*)d_in[14];
  const float* a2_kb = (const float*)d_in[15];
  const float* a2_qw = (const float*)d_in[16];
  const float* a2_qb = (const float*)d_in[17];
  const float* a2_ow = (const float*)d_in[18];
  const float* a2_ob = (const float*)d_in[19];
  const float* q_w   = (const float*)d_in[20];
  const float* q_b   = (const float*)d_in[21];
  short* ws = (short*)d_ws;

  prep_weights<<<164, 256, 0, stream>>>(
      enc_w, a1_vw, a1_kw, a1_qw, a1_ow, a2_vw, a2_kw, a2_qw, a2_ow, q_w, ws);

  dgn_main<<<4096 / G, 512, 0, stream>>>(
      x, mask, enc_b,
      a1_vb, a1_kb, a1_qb, a1_ob,
      a2_vb, a2_kb, a2_qb, a2_ob,
      q_b, ws, (float*)d_out);
}

// Round 4
// 290.168 us; speedup vs baseline: 1.1050x; 1.0794x over previous
//
#include <hip/hip_runtime.h>
#include <hip/hip_bf16.h>

typedef __attribute__((ext_vector_type(8))) short bf16x8;
typedef __attribute__((ext_vector_type(4))) short bf16x4;
typedef __attribute__((ext_vector_type(4))) float f32x4;

#define DEVI static __device__ __forceinline__

constexpr int NAG = 32, DIN = 256, HDIM = 128, ADIM = 32;

// ws layout (bf16 element offsets). Frag order serves both A- and B-orientation:
//   elem ((ks*NM + mt)*64 + lane)*8 + j  <->  W[ks*32 + (lane>>4)*8 + j][mt*16 + (lane&15)]
constexpr int WS_ENC = 0;                  // 256x128
constexpr int WS_H   = 32768;              // 8 mats x 16384
constexpr int WS_QW  = 32768 + 8 * 16384;  // 128x32
constexpr int WS_TOT = WS_QW + 4096;

// strides (shorts). Row byte-size must be 16B-multiple for ds_read_b128.
constexpr int SH = 136;   // h/Q/K/attout rows [32][136]
constexpr int SV = 40;    // vT rows [128][40]
constexpr int SA = 40;    // AT rows [32][40]
constexpr int SX = 264;   // x staging [32][264]

// LDS byte offsets: P0/P1/P2 = 8704 each, PV = 10240 -> 36352 B -> 4 blocks/CU
constexpr int L_P0 = 0;
constexpr int L_P1 = 8704;
constexpr int L_P2 = 17408;
constexpr int L_PV = 26112;
constexpr int L_TOT = 36352;

DEVI short f2bf(float f) {
  union { float f; unsigned u; } a; a.f = f;
  return (short)((a.u + 0x7fffu + ((a.u >> 16) & 1u)) >> 16);
}

// ---------------- weight prep: coalesced float4 reads, scattered 2B writes ----
__global__ void prep_weights(const float* __restrict__ enc_w,
                             const float* __restrict__ m0, const float* __restrict__ m1,
                             const float* __restrict__ m2, const float* __restrict__ m3,
                             const float* __restrict__ m4, const float* __restrict__ m5,
                             const float* __restrict__ m6, const float* __restrict__ m7,
                             const float* __restrict__ qw,
                             short* __restrict__ ws)
{
  const int blk = blockIdx.x, tid = threadIdx.x;
  const float* src; int base, NM, nsh, f4;
  if (blk < 32) { src = enc_w; base = WS_ENC; NM = 8; nsh = 7; f4 = blk * 256 + tid; }
  else if (blk < 160) {
    const int m = (blk - 32) >> 4;
    if      (m == 0) src = m0; else if (m == 1) src = m1;
    else if (m == 2) src = m2; else if (m == 3) src = m3;
    else if (m == 4) src = m4; else if (m == 5) src = m5;
    else if (m == 6) src = m6; else             src = m7;
    base = WS_H + (m << 14); NM = 8; nsh = 7; f4 = ((blk - 32) & 15) * 256 + tid;
  } else { src = qw; base = WS_QW; NM = 2; nsh = 5; f4 = (blk - 160) * 256 + tid; }
  const int s = f4 * 4;
  const int row = s >> nsh, col0 = s & ((1 << nsh) - 1);
  const float4 v = *(const float4*)(src + s);
  const int j = row & 7, ks = row >> 5, lhi = ((row >> 3) & 3) * 16;
  const float vv[4] = {v.x, v.y, v.z, v.w};
#pragma unroll
  for (int c = 0; c < 4; ++c) {
    const int col = col0 + c;
    const int mt = col >> 4, lane = lhi + (col & 15);
    ws[base + (((ks * NM + mt) * 64 + lane) << 3) + j] = f2bf(vv[c]);
  }
}

// ---------------- swapped linear on 4 waves: dst[agent][feat], wave = feat group -
// wave mg: m-tiles (features) mg*2+{0,1}; n-tiles (agents) {0,1}
template<int KSTEPS, bool RELU>
DEVI void linearSw4(const short* __restrict__ src, int sstride,
                    const short* __restrict__ wfrag, const float* __restrict__ bias,
                    short* __restrict__ dst,
                    int mg, int lr, int lq, int lane)
{
  f32x4 acc[2][2];
#pragma unroll
  for (int a = 0; a < 2; ++a)
#pragma unroll
    for (int b = 0; b < 2; ++b) acc[a][b] = (f32x4){0.f, 0.f, 0.f, 0.f};

  const bf16x8* wp = (const bf16x8*)wfrag;
#pragma unroll
  for (int ks = 0; ks < KSTEPS; ++ks) {
    bf16x8 hb[2];
#pragma unroll
    for (int b = 0; b < 2; ++b)
      hb[b] = *(const bf16x8*)(src + (b * 16 + lr) * sstride + ks * 32 + lq * 8);
#pragma unroll
    for (int a = 0; a < 2; ++a) {
      const bf16x8 wa = wp[(ks * 8 + mg * 2 + a) * 64 + lane];
#pragma unroll
      for (int b = 0; b < 2; ++b)
        acc[a][b] = __builtin_amdgcn_mfma_f32_16x16x32_bf16(wa, hb[b], acc[a][b], 0, 0, 0);
    }
  }
#pragma unroll
  for (int a = 0; a < 2; ++a) {
    const float4 bv = *(const float4*)(bias + (mg * 2 + a) * 16 + lq * 4);
    const float bb[4] = {bv.x, bv.y, bv.z, bv.w};
#pragma unroll
    for (int b = 0; b < 2; ++b) {
      bf16x4 s;
#pragma unroll
      for (int r = 0; r < 4; ++r) {
        float v = acc[a][b][r] + bb[r];
        if (RELU) v = fmaxf(v, 0.f);
        s[r] = f2bf(v);
      }
      *(bf16x4*)(dst + (b * 16 + lr) * SH + (mg * 2 + a) * 16 + lq * 4) = s;
    }
  }
}

// ---------------- fused QKV: one h-read pass feeds q,k (swapped) and v (normal) -
DEVI void qkv_pass4(const short* __restrict__ h,
                    const short* __restrict__ wq, const short* __restrict__ wk,
                    const short* __restrict__ wv,
                    const float* __restrict__ bq, const float* __restrict__ bk,
                    const float* __restrict__ bv,
                    short* __restrict__ Q, short* __restrict__ K, short* __restrict__ V,
                    int mg, int lr, int lq, int lane)
{
  f32x4 qa[2][2], ka[2][2], va[2][2];
#pragma unroll
  for (int a = 0; a < 2; ++a)
#pragma unroll
    for (int b = 0; b < 2; ++b) {
      qa[a][b] = (f32x4){0.f, 0.f, 0.f, 0.f};
      ka[a][b] = (f32x4){0.f, 0.f, 0.f, 0.f};
      va[a][b] = (f32x4){0.f, 0.f, 0.f, 0.f};
    }
  const bf16x8* wpq = (const bf16x8*)wq;
  const bf16x8* wpk = (const bf16x8*)wk;
  const bf16x8* wpv = (const bf16x8*)wv;
#pragma unroll
  for (int ks = 0; ks < 4; ++ks) {
    bf16x8 hf[2];
#pragma unroll
    for (int b = 0; b < 2; ++b)
      hf[b] = *(const bf16x8*)(h + (b * 16 + lr) * SH + ks * 32 + lq * 8);
#pragma unroll
    for (int a = 0; a < 2; ++a) {
      const bf16x8 wqf = wpq[(ks * 8 + mg * 2 + a) * 64 + lane];
      const bf16x8 wkf = wpk[(ks * 8 + mg * 2 + a) * 64 + lane];
      const bf16x8 wvf = wpv[(ks * 8 + mg * 2 + a) * 64 + lane];
#pragma unroll
      for (int b = 0; b < 2; ++b) {
        qa[a][b] = __builtin_amdgcn_mfma_f32_16x16x32_bf16(wqf, hf[b], qa[a][b], 0, 0, 0);
        ka[a][b] = __builtin_amdgcn_mfma_f32_16x16x32_bf16(wkf, hf[b], ka[a][b], 0, 0, 0);
        va[b][a] = __builtin_amdgcn_mfma_f32_16x16x32_bf16(hf[b], wvf, va[b][a], 0, 0, 0);
      }
    }
  }
  // q, k epilogues: lane holds 4 consecutive features for fixed agent
#pragma unroll
  for (int a = 0; a < 2; ++a) {
    const float4 bq4 = *(const float4*)(bq + (mg * 2 + a) * 16 + lq * 4);
    const float4 bk4 = *(const float4*)(bk + (mg * 2 + a) * 16 + lq * 4);
    const float qb4[4] = {bq4.x, bq4.y, bq4.z, bq4.w};
    const float kb4[4] = {bk4.x, bk4.y, bk4.z, bk4.w};
#pragma unroll
    for (int b = 0; b < 2; ++b) {
      bf16x4 sq, sk;
#pragma unroll
      for (int r = 0; r < 4; ++r) {
        sq[r] = f2bf(fmaxf(qa[a][b][r] + qb4[r], 0.f));
        sk[r] = f2bf(fmaxf(ka[a][b][r] + kb4[r], 0.f));
      }
      const int off = (b * 16 + lr) * SH + (mg * 2 + a) * 16 + lq * 4;
      *(bf16x4*)(Q + off) = sq;
      *(bf16x4*)(K + off) = sk;
    }
  }
  // v epilogue: normal orientation -> vT[feat][agent], 4 consecutive agents/lane
#pragma unroll
  for (int a = 0; a < 2; ++a) {
    const float bvv = bv[(mg * 2 + a) * 16 + lr];
#pragma unroll
    for (int b = 0; b < 2; ++b) {
      bf16x4 sv;
#pragma unroll
      for (int r = 0; r < 4; ++r)
        sv[r] = f2bf(fmaxf(va[b][a][r] + bvv, 0.f));
      *(bf16x4*)(V + ((mg * 2 + a) * 16 + lr) * SV + b * 16 + lq * 4) = sv;
    }
  }
}

// ---------------- scores + softmax on waves 0,1 (qt = wave), in-register -------
DEVI void scores_pass4(const short* __restrict__ Q, const short* __restrict__ K,
                       short* __restrict__ AT, const float* __restrict__ mask,
                       int b0, int qt, int lr, int lq)
{
  f32x4 sc[2];
  sc[0] = (f32x4){0.f, 0.f, 0.f, 0.f};
  sc[1] = (f32x4){0.f, 0.f, 0.f, 0.f};
#pragma unroll
  for (int ks = 0; ks < 4; ++ks) {
    const bf16x8 qf = *(const bf16x8*)(Q + (qt * 16 + lr) * SH + ks * 32 + lq * 8);
#pragma unroll
    for (int kt = 0; kt < 2; ++kt) {
      const bf16x8 kf = *(const bf16x8*)(K + (kt * 16 + lr) * SH + ks * 32 + lq * 8);
      sc[kt] = __builtin_amdgcn_mfma_f32_16x16x32_bf16(kf, qf, sc[kt], 0, 0, 0);
    }
  }
  // lane: q = qt*16+lr (fixed), k = kt*16 + lq*4 + r  (8 logits)
  const float* mp = mask + (size_t)b0 * (NAG * NAG) + (qt * 16 + lr) * 32;
  float l[2][4];
  float M = -3.0e38f;
#pragma unroll
  for (int kt = 0; kt < 2; ++kt) {
    const float4 m4 = *(const float4*)(mp + kt * 16 + lq * 4);
    const float mm[4] = {m4.x, m4.y, m4.z, m4.w};
#pragma unroll
    for (int r = 0; r < 4; ++r) {
      const float v = sc[kt][r] * mm[r] - 9e15f * (1.f - mm[r]);
      l[kt][r] = v;
      M = fmaxf(M, v);
    }
  }
  M = fmaxf(M, __shfl_xor(M, 16));
  M = fmaxf(M, __shfl_xor(M, 32));
  float e[2][4], T = 0.f;
#pragma unroll
  for (int kt = 0; kt < 2; ++kt)
#pragma unroll
    for (int r = 0; r < 4; ++r) { e[kt][r] = __expf(l[kt][r] - M); T += e[kt][r]; }
  T += __shfl_xor(T, 16);
  T += __shfl_xor(T, 32);
  const float rT = __frcp_rn(T);
#pragma unroll
  for (int kt = 0; kt < 2; ++kt) {
    bf16x4 s;
#pragma unroll
    for (int r = 0; r < 4; ++r) s[r] = f2bf(e[kt][r] * rT);
    *(bf16x4*)(AT + (qt * 16 + lr) * SA + kt * 16 + lq * 4) = s;
  }
}

// ---------------- PV: attout[q][feat] = att @ v  (A=vT, B=AT) -------------------
DEVI void pv_pass4(const short* __restrict__ V, const short* __restrict__ AT,
                   short* __restrict__ AO, int wave, int lr, int lq)
{
  bf16x8 atf[2];
#pragma unroll
  for (int qt = 0; qt < 2; ++qt)
    atf[qt] = *(const bf16x8*)(AT + (qt * 16 + lr) * SA + lq * 8);
#pragma unroll
  for (int fi = 0; fi < 2; ++fi) {
    const int f2 = wave * 2 + fi;
    const bf16x8 vf = *(const bf16x8*)(V + (f2 * 16 + lr) * SV + lq * 8);
#pragma unroll
    for (int qt = 0; qt < 2; ++qt) {
      const f32x4 p = __builtin_amdgcn_mfma_f32_16x16x32_bf16(
          vf, atf[qt], (f32x4){0.f, 0.f, 0.f, 0.f}, 0, 0, 0);
      bf16x4 s;
#pragma unroll
      for (int r = 0; r < 4; ++r) s[r] = f2bf(p[r]);
      *(bf16x4*)(AO + (qt * 16 + lr) * SH + f2 * 16 + lq * 4) = s;
    }
  }
}

DEVI void att_block4(const short* Rh, short* RQ, short* RK, short* RV,
                     short* RAT, short* RAO, short* Rout,
                     const short* wv, const short* wk, const short* wq, const short* wo,
                     const float* bv, const float* bk, const float* bq, const float* bo,
                     const float* __restrict__ mask, int b0,
                     int wave, int lr, int lq, int lane)
{
  qkv_pass4(Rh, wq, wk, wv, bq, bk, bv, RQ, RK, RV, wave, lr, lq, lane);
  __syncthreads();
  if (wave < 2) scores_pass4(RQ, RK, RAT, mask, b0, wave, lr, lq);
  __syncthreads();
  pv_pass4(RV, RAT, RAO, wave, lr, lq);
  __syncthreads();
  linearSw4<4, true>(RAO, SH, wo, bo, Rout, wave, lr, lq, lane);
  __syncthreads();
}

// ---------------- fused forward: one block (256 thr) = 1 batch element ---------
__global__ __launch_bounds__(256, 4)
void dgn_main(const float* __restrict__ x, const float* __restrict__ mask,
              const float* __restrict__ enc_b,
              const float* __restrict__ b1v, const float* __restrict__ b1k,
              const float* __restrict__ b1q, const float* __restrict__ b1o,
              const float* __restrict__ b2v, const float* __restrict__ b2k,
              const float* __restrict__ b2q, const float* __restrict__ b2o,
              const float* __restrict__ qb,
              const short* __restrict__ wf,
              float* __restrict__ out)
{
  __shared__ __align__(16) char smem[L_TOT];
  short* P0 = (short*)(smem + L_P0);
  short* P1 = (short*)(smem + L_P1);
  short* P2 = (short*)(smem + L_P2);
  short* PV = (short*)(smem + L_PV);
  short* XB = (short*)(smem + L_P1);   // x staging [32][264] = 16896 B over P1+P2

  const int tid = threadIdx.x;
  const int wave = tid >> 6, lane = tid & 63;
  const int lr = lane & 15, lq = lane >> 4;
  const int b0 = blockIdx.x;

  // stage x (fp32 -> bf16)
  {
    const float4* xsrc = (const float4*)(x + (size_t)b0 * NAG * DIN);
#pragma unroll
    for (int it = 0; it < 8; ++it) {
      const int q4 = tid + it * 256;
      const float4 v = xsrc[q4];
      bf16x4 s;
      s[0] = f2bf(v.x); s[1] = f2bf(v.y); s[2] = f2bf(v.z); s[3] = f2bf(v.w);
      *(bf16x4*)(XB + (q4 >> 6) * SX + (q4 & 63) * 4) = s;
    }
  }
  __syncthreads();

  // encoder: h1[agent][feat] -> P0   (reads XB = P1+P2)
  linearSw4<8, true>(XB, SX, wf + WS_ENC, enc_b, P0, wave, lr, lq, lane);
  __syncthreads();

  // att1: h1=P0 -> Q=P1, K=P2, V=PV; AT=P0 (h1 dead); attout=P1 (Q dead); h2=P2 (K dead)
  att_block4(P0, P1, P2, PV, P0, P1, P2,
             wf + WS_H + 0 * 16384, wf + WS_H + 1 * 16384,
             wf + WS_H + 2 * 16384, wf + WS_H + 3 * 16384,
             b1v, b1k, b1q, b1o, mask, b0, wave, lr, lq, lane);

  // att2: h2=P2 -> Q=P0, K=P1, V=PV; AT=P2; attout=P0; h3=P1
  att_block4(P2, P0, P1, PV, P2, P0, P1,
             wf + WS_H + 4 * 16384, wf + WS_H + 5 * 16384,
             wf + WS_H + 6 * 16384, wf + WS_H + 7 * 16384,
             b2v, b2k, b2q, b2o, mask, b0, wave, lr, lq, lane);

  // head on waves 0,1: wave = agent-tile, both action-tiles -> full 128B lines
  if (wave < 2) {
    f32x4 ha[2];
    ha[0] = (f32x4){0.f, 0.f, 0.f, 0.f};
    ha[1] = (f32x4){0.f, 0.f, 0.f, 0.f};
    const bf16x8* wp = (const bf16x8*)(wf + WS_QW);
#pragma unroll
    for (int ks = 0; ks < 4; ++ks) {
      const bf16x8 hf = *(const bf16x8*)(P1 + (wave * 16 + lr) * SH + ks * 32 + lq * 8);
#pragma unroll
      for (int a = 0; a < 2; ++a)
        ha[a] = __builtin_amdgcn_mfma_f32_16x16x32_bf16(wp[(ks * 2 + a) * 64 + lane], hf, ha[a], 0, 0, 0);
    }
    float* op = out + ((size_t)b0 * NAG + wave * 16 + lr) * ADIM;
#pragma unroll
    for (int a = 0; a < 2; ++a) {
      const float4 bv4 = *(const float4*)(qb + a * 16 + lq * 4);
      float4 o;
      o.x = ha[a][0] + bv4.x; o.y = ha[a][1] + bv4.y;
      o.z = ha[a][2] + bv4.z; o.w = ha[a][3] + bv4.w;
      *(float4*)(op + a * 16 + lq * 4) = o;
    }
  }
}

extern "C" void kernel_launch(void* const* d_in, const int* in_sizes, int n_in,
                              void* d_out, int out_size, void* d_ws, size_t ws_size,
                              hipStream_t stream)
{
  const float* x     = (const float*)d_in[0];
  const float* mask  = (const float*)d_in[1];
  const float* enc_w = (const float*)d_in[2];
  const float* enc_b = (const float*)d_in[3];
  const float* a1_vw = (const float*)d_in[4];
  const float* a1_vb = (const float*)d_in[5];
  const float* a1_kw = (const float*)d_in[6];
  const float* a1_kb = (const float*)d_in[7];
  const float* a1_qw = (const float*)d_in[8];
  const float* a1_qb = (const float*)d_in[9];
  const float* a1_ow = (const float*)d_in[10];
  const float* a1_ob = (const float*)d_in[11];
  const float* a2_vw = (const float*)d_in[12];
  const float* a2_vb = (const float*)d_in[13];
  const float* a2_kw = (const float*)d_in[14];
  const float* a2_kb = (const float*)d_in[15];
  const float* a2_qw = (const float*)d_in[16];
  const float* a2_qb = (const float*)d_in[17];
  const float* a2_ow = (const float*)d_in[18];
  const float* a2_ob = (const float*)d_in[19];
  const float* q_w   = (const float*)d_in[20];
  const float* q_b   = (const float*)d_in[21];
  short* ws = (short*)d_ws;

  prep_weights<<<164, 256, 0, stream>>>(
      enc_w, a1_vw, a1_kw, a1_qw, a1_ow, a2_vw, a2_kw, a2_qw, a2_ow, q_w, ws);

  dgn_main<<<4096, 256, 0, stream>>>(
      x, mask, enc_b,
      a1_vb, a1_kb, a1_qb, a1_ob,
      a2_vb, a2_kb, a2_qb, a2_ob,
      q_b, ws, (float*)d_out);
}